// Round 4
// baseline (552.622 us; speedup 1.0000x reference)
//
#include <hip/hip_runtime.h>
#include <hip/hip_bf16.h>

#define BB 8
#define CC 256
#define NN 4096
#define KP 64   // projection dim K = C/4
#define LOG2E 1.44269504088896f

typedef _Float16 f16x8 __attribute__((ext_vector_type(8)));
typedef _Float16 f16x4 __attribute__((ext_vector_type(4)));
typedef float    f32x4 __attribute__((ext_vector_type(4)));

#define MFMA16(a, b, c) __builtin_amdgcn_mfma_f32_16x16x32_f16((a), (b), (c), 0, 0, 0)

// exp2 (g is pre-scaled by log2e in proj, so softmax runs in base-2)
__device__ __forceinline__ float fast_exp2(float x) {
#if __has_builtin(__builtin_amdgcn_exp2f)
    return __builtin_amdgcn_exp2f(x);
#else
    return __expf(x * 0.69314718055994531f);
#endif
}

// 16-lane (DPP-row) rotate reductions: VALU-speed, off the LDS pipe
template<int CTRL>
__device__ __forceinline__ float dpp_ror_f(float x) {
    return __int_as_float(__builtin_amdgcn_update_dpp(
        0, __float_as_int(x), CTRL, 0xF, 0xF, true));
}
__device__ __forceinline__ float max16(float x) {
    x = fmaxf(x, dpp_ror_f<0x128>(x));
    x = fmaxf(x, dpp_ror_f<0x124>(x));
    x = fmaxf(x, dpp_ror_f<0x122>(x));
    x = fmaxf(x, dpp_ror_f<0x121>(x));
    return x;
}
__device__ __forceinline__ float sum16(float x) {
    x += dpp_ror_f<0x128>(x);
    x += dpp_ror_f<0x124>(x);
    x += dpp_ror_f<0x122>(x);
    x += dpp_ror_f<0x121>(x);
    return x;
}

// ---------------------------------------------------------------------------
// Kernel 0: WF|WG|WH fp32 -> concatenated fp16 W16[384][256].
// ---------------------------------------------------------------------------
__global__ __launch_bounds__(256) void wconv_kernel(
    const float* __restrict__ WF, const float* __restrict__ WG,
    const float* __restrict__ WH, _Float16* __restrict__ W16)
{
    int gid = blockIdx.x * 256 + threadIdx.x;
    int i4  = gid * 4;
    const float* src;
    if (i4 < 64 * CC)        src = WF + i4;
    else if (i4 < 128 * CC)  src = WG + (i4 - 64 * CC);
    else                     src = WH + (i4 - 128 * CC);
    float4 v = *(const float4*)src;
    f16x4 o = { (_Float16)v.x, (_Float16)v.y, (_Float16)v.z, (_Float16)v.w };
    *(f16x4*)(W16 + i4) = o;
}

// ---------------------------------------------------------------------------
// Kernel 1: fp16 MFMA projection, 64-token tiles.
// D[384 out][64 tok] = W16 x feat. Wave w owns out-rows [w*96, w*96+96).
// g rows are pre-scaled by log2e (softmax invariant; lets attn use raw exp2).
// ---------------------------------------------------------------------------
__global__ __launch_bounds__(256, 3) void proj16_kernel(
    const float* __restrict__ feat, const _Float16* __restrict__ W16,
    _Float16* __restrict__ fb, _Float16* __restrict__ gb,
    _Float16* __restrict__ hT)
{
    __shared__ __align__(16) _Float16 ft[64][264];
    const int b = blockIdx.y, n0 = blockIdx.x * 64, t = threadIdx.x;

    // stage feat[b][:, n0..n0+63] -> ft[tok][c] fp16 (transpose + convert)
    #pragma unroll
    for (int i = 0; i < 16; i++) {
        int v = t + i * 256, c = v >> 4, nq = v & 15;
        float4 x = *(const float4*)(feat + ((size_t)b * CC + c) * NN + n0 + nq * 4);
        ft[nq * 4 + 0][c] = (_Float16)x.x;
        ft[nq * 4 + 1][c] = (_Float16)x.y;
        ft[nq * 4 + 2][c] = (_Float16)x.z;
        ft[nq * 4 + 3][c] = (_Float16)x.w;
    }
    __syncthreads();

    const int w = t >> 6, lane = t & 63, quad = lane >> 4, ln = lane & 15;
    const int rowbase = w * 96;

    f32x4 acc[6][4] = {};
    #pragma unroll
    for (int ks = 0; ks < 8; ks++) {
        const int c0 = ks * 32;
        f16x8 bfr[4];
        #pragma unroll
        for (int tf = 0; tf < 4; tf++)
            bfr[tf] = *(const f16x8*)&ft[tf * 16 + ln][c0 + quad * 8];
        #pragma unroll
        for (int af = 0; af < 6; af++) {
            f16x8 a = *(const f16x8*)(W16 + (size_t)(rowbase + af * 16 + ln) * CC + c0 + quad * 8);
            #pragma unroll
            for (int tf = 0; tf < 4; tf++)
                acc[af][tf] = MFMA16(a, bfr[tf], acc[af][tf]);
        }
    }

    // C/D layout: col(tok)=ln, row(out)=quad*4+r
    #pragma unroll
    for (int af = 0; af < 6; af++) {
        const int orow0 = rowbase + af * 16 + quad * 4;   // wave-uniform range
        if (orow0 < 64) {
            #pragma unroll
            for (int tf = 0; tf < 4; tf++) {
                const int tok = n0 + tf * 16 + ln;
                f16x4 pk = { (_Float16)acc[af][tf][0], (_Float16)acc[af][tf][1],
                             (_Float16)acc[af][tf][2], (_Float16)acc[af][tf][3] };
                *(f16x4*)(fb + ((size_t)b * NN + tok) * KP + orow0) = pk;
            }
        } else if (orow0 < 128) {
            #pragma unroll
            for (int tf = 0; tf < 4; tf++) {
                const int tok = n0 + tf * 16 + ln;
                f16x4 pk = { (_Float16)(acc[af][tf][0] * LOG2E),
                             (_Float16)(acc[af][tf][1] * LOG2E),
                             (_Float16)(acc[af][tf][2] * LOG2E),
                             (_Float16)(acc[af][tf][3] * LOG2E) };
                *(f16x4*)(gb + ((size_t)b * NN + tok) * KP + (orow0 - 64)) = pk;
            }
        } else {
            #pragma unroll
            for (int r = 0; r < 4; r++) {
                const int d = orow0 - 128 + r;
                f16x4 pk = { (_Float16)acc[af][0][r], (_Float16)acc[af][1][r],
                             (_Float16)acc[af][2][r], (_Float16)acc[af][3][r] };
                *(f16x4*)(hT + ((size_t)b * CC + d) * NN + n0 + ln * 4) = pk;
            }
        }
    }
}

// ---------------------------------------------------------------------------
// Kernel 2: fp16 MFMA flash attention, Tq=64, Tm=64, 4 symmetric waves.
// Round-1 structure (2 barriers/iter, 84 VGPR) + KV-SPLIT over blockIdx.z:
// NSPLIT=2 -> 1024 blocks -> 4 blocks/CU, 16 waves/CU (was 2 blocks, 8 waves).
// The per-iter barriers phase-lock each block's waves into MFMA/VALU/LDS
// bursts; 4 independent blocks per CU de-phase and overlap those bursts.
// Traffic per unit work is unchanged (m-range is split, not duplicated).
// Split epilogue writes l-normalized fp16 partial O + per-row base-2 LSE;
// combine_kernel merges the two halves (numerically exact online-softmax
// merge). NSPLIT=1 instantiation = the verified round-1 kernel (ws fallback).
// ---------------------------------------------------------------------------
template<int NSPLIT>
__global__ __launch_bounds__(256, 4) void attn16_kernel(
    const _Float16* __restrict__ fb, const _Float16* __restrict__ gb,
    const _Float16* __restrict__ hT, const float* __restrict__ inp,
    const float* __restrict__ gamma, float* __restrict__ out,
    _Float16* __restrict__ oP, float* __restrict__ lseP)
{
    constexpr int ITERS = (NN / 64) / NSPLIT;
    __shared__ __align__(16) _Float16 g_s[64][72];
    __shared__ __align__(16) _Float16 f_s[64][72];
    __shared__ __align__(16) _Float16 p_s[64][72];
    __shared__ float alpha_s[64];
    __shared__ float l_s[64];
    __shared__ float chg_s[4];

    const int b = blockIdx.x, q0 = blockIdx.y * 64, t = threadIdx.x;
    const int z = (NSPLIT > 1) ? blockIdx.z : 0;
    const int mtbase = z * ITERS;
    const int w = t >> 6, lane = t & 63, quad = lane >> 4, ln = lane & 15;
    const int row = t >> 2, kq = t & 3;
    const int dbase = w * 64;

    // stage g tile [64 q][64 k] once (already log2e-scaled by proj)
    {
        const _Float16* src = gb + ((size_t)b * NN + q0 + row) * KP + kq * 16;
        *(f16x8*)&g_s[row][kq * 16]     = *(const f16x8*)(src);
        *(f16x8*)&g_s[row][kq * 16 + 8] = *(const f16x8*)(src + 8);
    }
    // preload f tile 0 (of this split's range) into registers
    f16x8 fr0, fr1;
    {
        const _Float16* src = fb + ((size_t)b * NN + mtbase * 64 + row) * KP + kq * 16;
        fr0 = *(const f16x8*)(src);
        fr1 = *(const f16x8*)(src + 8);
    }
    __syncthreads();   // g_s visible

    // hoist loop-invariant A-fragments of QK^T
    f16x8 ag[2];
    ag[0] = *(const f16x8*)&g_s[w * 16 + ln][quad * 8];
    ag[1] = *(const f16x8*)&g_s[w * 16 + ln][32 + quad * 8];

    float m_run[4] = {-1e30f, -1e30f, -1e30f, -1e30f};
    float l_run[4] = {0.f, 0.f, 0.f, 0.f};   // per-lane PARTIAL row sums
    f32x4 acc[4][4] = {};
    f16x8 hv[2][4];

    #pragma unroll 1
    for (int mtl = 0; mtl < ITERS; mtl++) {
        const int m0 = (mtbase + mtl) * 64;

        // current f tile regs -> LDS
        *(f16x8*)&f_s[row][kq * 16]     = fr0;
        *(f16x8*)&f_s[row][kq * 16 + 8] = fr1;
        __syncthreads();   // barrier 1: f_s ready

        // issue prefetches NOW: they drain at barrier 2, covered by QK+softmax
        {
            const int m0n = (mtbase + ((mtl + 1) & (ITERS - 1))) * 64;   // wrap in-range
            const _Float16* srcf = fb + ((size_t)b * NN + m0n + row) * KP + kq * 16;
            fr0 = *(const f16x8*)(srcf);
            fr1 = *(const f16x8*)(srcf + 8);
            #pragma unroll
            for (int ks = 0; ks < 2; ks++)
                #pragma unroll
                for (int df = 0; df < 4; df++)
                    hv[ks][df] = *(const f16x8*)(hT +
                        ((size_t)b * CC + dbase + df * 16 + ln) * NN + m0 + ks * 32 + quad * 8);
        }

        // ---- QK^T for this wave's q-stripe ----
        f32x4 S[4] = {};
        #pragma unroll
        for (int ks = 0; ks < 2; ks++) {
            #pragma unroll
            for (int mf = 0; mf < 4; mf++) {
                f16x8 bf = *(const f16x8*)&f_s[mf * 16 + ln][ks * 32 + quad * 8];
                S[mf] = MFMA16(ag[ks], bf, S[mf]);
            }
        }

        // ---- deferred-max online softmax (base-2), rows q = w*16+quad*4+r --
        float pmax[4];
        bool upd = false;
        #pragma unroll
        for (int r = 0; r < 4; r++) {
            pmax[r] = fmaxf(fmaxf(S[0][r], S[1][r]), fmaxf(S[2][r], S[3][r]));
            upd |= (pmax[r] > m_run[r] + 10.0f);
        }
        const bool wave_upd = (__ballot(upd) != 0ull);   // wave-uniform
        if (wave_upd) {
            #pragma unroll
            for (int r = 0; r < 4; r++) {
                float mx   = max16(pmax[r]);
                float mnew = fmaxf(m_run[r], mx);
                float al   = fast_exp2(m_run[r] - mnew);
                l_run[r] *= al;
                m_run[r]  = mnew;
                if (ln == 0) alpha_s[w * 16 + quad * 4 + r] = al;
            }
        }
        if (lane == 0) chg_s[w] = wave_upd ? 1.0f : 0.0f;
        #pragma unroll
        for (int r = 0; r < 4; r++) {
            float p0 = fast_exp2(S[0][r] - m_run[r]);
            float p1 = fast_exp2(S[1][r] - m_run[r]);
            float p2 = fast_exp2(S[2][r] - m_run[r]);
            float p3 = fast_exp2(S[3][r] - m_run[r]);
            l_run[r] += (p0 + p1) + (p2 + p3);   // per-lane partial, reduced at end
            f16x4 pk = { (_Float16)p0, (_Float16)p1, (_Float16)p2, (_Float16)p3 };
            *(f16x4*)&p_s[w * 16 + quad * 4 + r][ln * 4] = pk;   // permuted col m' = ln*4 + mf
        }
        __syncthreads();   // barrier 2: p_s/chg_s/alpha_s visible (+ prefetch drain)

        // ---- rescale, gated per wave-of-origin (wave-uniform branches) ----
        {
            float chg[4] = { chg_s[0], chg_s[1], chg_s[2], chg_s[3] };
            #pragma unroll
            for (int qf = 0; qf < 4; qf++) {
                if (chg[qf] != 0.0f) {
                    #pragma unroll
                    for (int r = 0; r < 4; r++) {
                        float al = alpha_s[qf * 16 + quad * 4 + r];
                        #pragma unroll
                        for (int df = 0; df < 4; df++)
                            acc[qf][df][r] *= al;
                    }
                }
            }
        }

        // ---- PV: P x h^T over this wave's 64 channels ----
        #pragma unroll
        for (int ks = 0; ks < 2; ks++) {
            #pragma unroll
            for (int qf = 0; qf < 4; qf++) {
                f16x8 ap = *(const f16x8*)&p_s[qf * 16 + ln][ks * 32 + quad * 8];
                #pragma unroll
                for (int df = 0; df < 4; df++)
                    acc[qf][df] = MFMA16(ap, hv[ks][df], acc[qf][df]);
            }
        }
    }

    // ---- finish l (deferred 16-lane reduce), exchange across waves ----
    #pragma unroll
    for (int r = 0; r < 4; r++) {
        float lt = sum16(l_run[r]);
        if (ln == 0) {
            l_s[w * 16 + quad * 4 + r] = lt;
            if (NSPLIT > 1)   // per-row base-2 LSE for the combine
                lseP[(size_t)z * BB * NN + (size_t)b * NN + q0 + w * 16 + quad * 4 + r]
                    = m_run[r] + __log2f(lt);
        }
    }
    __syncthreads();

    if constexpr (NSPLIT == 1) {
        const float gam = gamma[0];
        #pragma unroll
        for (int qf = 0; qf < 4; qf++) {
            #pragma unroll
            for (int r = 0; r < 4; r++) {
                const int q = qf * 16 + quad * 4 + r;
                const float linv = 1.0f / l_s[q];
                #pragma unroll
                for (int df = 0; df < 4; df++) {
                    const int d = dbase + df * 16 + ln;
                    size_t idx = ((size_t)b * NN + q0 + q) * CC + d;
                    out[idx] = fmaf(gam, acc[qf][df][r] * linv, inp[idx]);
                }
            }
        }
    } else {
        // normalized fp16 partial O (values are convex combos of h: |o|<~10, fp16-safe)
        _Float16* oPz = oP + (size_t)z * BB * NN * CC;
        #pragma unroll
        for (int qf = 0; qf < 4; qf++) {
            #pragma unroll
            for (int r = 0; r < 4; r++) {
                const int q = qf * 16 + quad * 4 + r;
                const float linv = 1.0f / l_s[q];
                #pragma unroll
                for (int df = 0; df < 4; df++) {
                    const int d = dbase + df * 16 + ln;
                    oPz[((size_t)b * NN + q0 + q) * CC + d] = (_Float16)(acc[qf][df][r] * linv);
                }
            }
        }
    }
}

// ---------------------------------------------------------------------------
// Kernel 3: merge the 2 KV-split halves: out = gamma * (w0*o0 + w1*o1) + inp,
// w_s = 2^(lse_s - max lse) normalized. Pure streaming, ~96 MB traffic.
// ---------------------------------------------------------------------------
__global__ __launch_bounds__(256) void combine_kernel(
    const _Float16* __restrict__ oP, const float* __restrict__ lseP,
    const float* __restrict__ inp, const float* __restrict__ gamma,
    float* __restrict__ out)
{
    const int gid = blockIdx.x * 256 + threadIdx.x;   // over B*N*C/8
    const int rowi = gid >> 5;                        // b*NN + q
    const int d0 = (gid & 31) * 8;
    const size_t base = (size_t)rowi * CC + d0;

    float l0 = lseP[rowi];
    float l1 = lseP[(size_t)BB * NN + rowi];
    float M  = fmaxf(l0, l1);
    float w0 = fast_exp2(l0 - M), w1 = fast_exp2(l1 - M);
    float inv = 1.0f / (w0 + w1);
    w0 *= inv; w1 *= inv;

    f16x8 a0 = *(const f16x8*)(oP + base);
    f16x8 a1 = *(const f16x8*)(oP + (size_t)BB * NN * CC + base);
    const float gam = gamma[0];

    float4 i0 = *(const float4*)(inp + base);
    float4 i1 = *(const float4*)(inp + base + 4);
    float4 o0, o1;
    o0.x = fmaf(gam, w0 * (float)a0[0] + w1 * (float)a1[0], i0.x);
    o0.y = fmaf(gam, w0 * (float)a0[1] + w1 * (float)a1[1], i0.y);
    o0.z = fmaf(gam, w0 * (float)a0[2] + w1 * (float)a1[2], i0.z);
    o0.w = fmaf(gam, w0 * (float)a0[3] + w1 * (float)a1[3], i0.w);
    o1.x = fmaf(gam, w0 * (float)a0[4] + w1 * (float)a1[4], i1.x);
    o1.y = fmaf(gam, w0 * (float)a0[5] + w1 * (float)a1[5], i1.y);
    o1.z = fmaf(gam, w0 * (float)a0[6] + w1 * (float)a1[6], i1.z);
    o1.w = fmaf(gam, w0 * (float)a0[7] + w1 * (float)a1[7], i1.w);
    *(float4*)(out + base)     = o0;
    *(float4*)(out + base + 4) = o1;
}

// ---------------------------------------------------------------------------
extern "C" void kernel_launch(void* const* d_in, const int* in_sizes, int n_in,
                              void* d_out, int out_size, void* d_ws, size_t ws_size,
                              hipStream_t stream) {
    const float* input = (const float*)d_in[0];
    const float* nms   = (const float*)d_in[1];
    const float* WF    = (const float*)d_in[2];
    const float* WG    = (const float*)d_in[3];
    const float* WH    = (const float*)d_in[4];
    const float* gamma = (const float*)d_in[5];
    float* out = (float*)d_out;

    // workspace: W16 192KB | fb 4MB | gb 4MB | hT 16MB | oP 2x16MB | lse 2x128KB
    char* ws = (char*)d_ws;
    _Float16* W16  = (_Float16*)ws;
    _Float16* fb16 = (_Float16*)(ws + 196608);
    _Float16* gb16 = (_Float16*)(ws + 196608 + 4194304);
    _Float16* hT16 = (_Float16*)(ws + 196608 + 2 * 4194304);
    const size_t base_end = 196608 + 2 * 4194304 + (size_t)2 * BB * NN * CC; // hT end
    _Float16* oP   = (_Float16*)(ws + base_end);
    float*    lseP = (float*)(ws + base_end + (size_t)2 * 2 * BB * NN * CC);
    const size_t need = base_end + (size_t)2 * 2 * BB * NN * CC + (size_t)2 * 4 * BB * NN;

    wconv_kernel<<<96, 256, 0, stream>>>(WF, WG, WH, W16);
    proj16_kernel<<<dim3(NN / 64, BB), 256, 0, stream>>>(nms, W16, fb16, gb16, hT16);

    if (ws_size >= need) {
        // KV-split x2: 1024 blocks -> 4 blocks/CU, then streaming combine
        attn16_kernel<2><<<dim3(BB, NN / 64, 2), 256, 0, stream>>>(
            fb16, gb16, hT16, input, gamma, out, oP, lseP);
        combine_kernel<<<(BB * NN * CC / 8) / 256, 256, 0, stream>>>(
            oP, lseP, input, gamma, out);
    } else {
        // fallback: verified single-pass round-1 kernel
        attn16_kernel<1><<<dim3(BB, NN / 64), 256, 0, stream>>>(
            fb16, gb16, hT16, input, gamma, out, oP, lseP);
    }
}

// Round 5
// 372.945 us; speedup vs baseline: 1.4818x; 1.4818x over previous
//
#include <hip/hip_runtime.h>
#include <hip/hip_bf16.h>

#define BB 8
#define CC 256
#define NN 4096
#define KP 64   // projection dim K = C/4
#define LOG2E 1.44269504088896f

typedef _Float16 f16x8 __attribute__((ext_vector_type(8)));
typedef _Float16 f16x4 __attribute__((ext_vector_type(4)));
typedef float    f32x4 __attribute__((ext_vector_type(4)));

#define MFMA16(a, b, c) __builtin_amdgcn_mfma_f32_16x16x32_f16((a), (b), (c), 0, 0, 0)

// exp2 (g is pre-scaled by log2e in proj, so softmax runs in base-2)
__device__ __forceinline__ float fast_exp2(float x) {
#if __has_builtin(__builtin_amdgcn_exp2f)
    return __builtin_amdgcn_exp2f(x);
#else
    return __expf(x * 0.69314718055994531f);
#endif
}

// 16-lane (DPP-row) rotate reductions: VALU-speed, off the LDS pipe
template<int CTRL>
__device__ __forceinline__ float dpp_ror_f(float x) {
    return __int_as_float(__builtin_amdgcn_update_dpp(
        0, __float_as_int(x), CTRL, 0xF, 0xF, true));
}
__device__ __forceinline__ float max16(float x) {
    x = fmaxf(x, dpp_ror_f<0x128>(x));
    x = fmaxf(x, dpp_ror_f<0x124>(x));
    x = fmaxf(x, dpp_ror_f<0x122>(x));
    x = fmaxf(x, dpp_ror_f<0x121>(x));
    return x;
}
__device__ __forceinline__ float sum16(float x) {
    x += dpp_ror_f<0x128>(x);
    x += dpp_ror_f<0x124>(x);
    x += dpp_ror_f<0x122>(x);
    x += dpp_ror_f<0x121>(x);
    return x;
}

// ---------------------------------------------------------------------------
// Kernel 0: WF|WG|WH fp32 -> concatenated fp16 W16[384][256].
// ---------------------------------------------------------------------------
__global__ __launch_bounds__(256) void wconv_kernel(
    const float* __restrict__ WF, const float* __restrict__ WG,
    const float* __restrict__ WH, _Float16* __restrict__ W16)
{
    int gid = blockIdx.x * 256 + threadIdx.x;
    int i4  = gid * 4;
    const float* src;
    if (i4 < 64 * CC)        src = WF + i4;
    else if (i4 < 128 * CC)  src = WG + (i4 - 64 * CC);
    else                     src = WH + (i4 - 128 * CC);
    float4 v = *(const float4*)src;
    f16x4 o = { (_Float16)v.x, (_Float16)v.y, (_Float16)v.z, (_Float16)v.w };
    *(f16x4*)(W16 + i4) = o;
}

// ---------------------------------------------------------------------------
// Kernel 1: fp16 MFMA projection, 64-token tiles.
// D[384 out][64 tok] = W16 x feat. Wave w owns out-rows [w*96, w*96+96).
// g rows are pre-scaled by log2e (softmax invariant; lets attn use raw exp2).
// hT is stored sigma-permuted within each 64-token tile (col c <-> token
// (c&3)*16 + c>>2), matching p_s's permuted column order in attention.
// ---------------------------------------------------------------------------
__global__ __launch_bounds__(256, 3) void proj16_kernel(
    const float* __restrict__ feat, const _Float16* __restrict__ W16,
    _Float16* __restrict__ fb, _Float16* __restrict__ gb,
    _Float16* __restrict__ hT)
{
    __shared__ __align__(16) _Float16 ft[64][264];
    const int b = blockIdx.y, n0 = blockIdx.x * 64, t = threadIdx.x;

    // stage feat[b][:, n0..n0+63] -> ft[tok][c] fp16 (transpose + convert)
    #pragma unroll
    for (int i = 0; i < 16; i++) {
        int v = t + i * 256, c = v >> 4, nq = v & 15;
        float4 x = *(const float4*)(feat + ((size_t)b * CC + c) * NN + n0 + nq * 4);
        ft[nq * 4 + 0][c] = (_Float16)x.x;
        ft[nq * 4 + 1][c] = (_Float16)x.y;
        ft[nq * 4 + 2][c] = (_Float16)x.z;
        ft[nq * 4 + 3][c] = (_Float16)x.w;
    }
    __syncthreads();

    const int w = t >> 6, lane = t & 63, quad = lane >> 4, ln = lane & 15;
    const int rowbase = w * 96;

    f32x4 acc[6][4] = {};
    #pragma unroll
    for (int ks = 0; ks < 8; ks++) {
        const int c0 = ks * 32;
        f16x8 bfr[4];
        #pragma unroll
        for (int tf = 0; tf < 4; tf++)
            bfr[tf] = *(const f16x8*)&ft[tf * 16 + ln][c0 + quad * 8];
        #pragma unroll
        for (int af = 0; af < 6; af++) {
            f16x8 a = *(const f16x8*)(W16 + (size_t)(rowbase + af * 16 + ln) * CC + c0 + quad * 8);
            #pragma unroll
            for (int tf = 0; tf < 4; tf++)
                acc[af][tf] = MFMA16(a, bfr[tf], acc[af][tf]);
        }
    }

    // C/D layout: col(tok)=ln, row(out)=quad*4+r
    #pragma unroll
    for (int af = 0; af < 6; af++) {
        const int orow0 = rowbase + af * 16 + quad * 4;   // wave-uniform range
        if (orow0 < 64) {
            #pragma unroll
            for (int tf = 0; tf < 4; tf++) {
                const int tok = n0 + tf * 16 + ln;
                f16x4 pk = { (_Float16)acc[af][tf][0], (_Float16)acc[af][tf][1],
                             (_Float16)acc[af][tf][2], (_Float16)acc[af][tf][3] };
                *(f16x4*)(fb + ((size_t)b * NN + tok) * KP + orow0) = pk;
            }
        } else if (orow0 < 128) {
            #pragma unroll
            for (int tf = 0; tf < 4; tf++) {
                const int tok = n0 + tf * 16 + ln;
                f16x4 pk = { (_Float16)(acc[af][tf][0] * LOG2E),
                             (_Float16)(acc[af][tf][1] * LOG2E),
                             (_Float16)(acc[af][tf][2] * LOG2E),
                             (_Float16)(acc[af][tf][3] * LOG2E) };
                *(f16x4*)(gb + ((size_t)b * NN + tok) * KP + (orow0 - 64)) = pk;
            }
        } else {
            #pragma unroll
            for (int r = 0; r < 4; r++) {
                const int d = orow0 - 128 + r;
                f16x4 pk = { (_Float16)acc[af][0][r], (_Float16)acc[af][1][r],
                             (_Float16)acc[af][2][r], (_Float16)acc[af][3][r] };
                *(f16x4*)(hT + ((size_t)b * CC + d) * NN + n0 + ln * 4) = pk;
            }
        }
    }
}

// ---------------------------------------------------------------------------
// Kernel 2: fp16 MFMA flash attention, Tq=32, Tm=64, 4 waves.
// OCCUPANCY build: grid = 8 x 128 = 1024 blocks; per-wave state trimmed to
// fit 4 blocks/CU (16 waves/CU) at the 128-reg step: acc 32 (q=32 tile),
// hv ks-split 16 (reload ks=1 mid-PV), ag 16, fr 8 -> ~114 peak.
// Waves 0,1 compute QK^T (16-row q-stripes) + softmax; all 4 waves stage f,
// prefetch, and run PV over their own 64 channels. The waves-2,3 wait at
// barrier 2 is covered by the 4 co-resident blocks de-phasing the pipes
// (the point of this build: R1/R2 showed all pipes <=50% at 2 blocks/CU).
// Deferred-max softmax (THR=10, base-2) + lazy l-reduction as in round 1.
// ---------------------------------------------------------------------------
__global__ __launch_bounds__(256, 4) void attn16_kernel(
    const _Float16* __restrict__ fb, const _Float16* __restrict__ gb,
    const _Float16* __restrict__ hT, const float* __restrict__ inp,
    const float* __restrict__ gamma, float* __restrict__ out)
{
    __shared__ __align__(16) _Float16 g_s[32][72];
    __shared__ __align__(16) _Float16 f_s[64][72];
    __shared__ __align__(16) _Float16 p_s[32][72];
    __shared__ float alpha_s[32];
    __shared__ float l_s[32];
    __shared__ float chg_s[2];

    const int b = blockIdx.x, q0 = blockIdx.y * 32, t = threadIdx.x;
    const int w = t >> 6, lane = t & 63, quad = lane >> 4, ln = lane & 15;
    const int row = t >> 2, kq = t & 3;      // f staging: 64 rows x 32B
    const int dbase = w * 64;

    // stage g tile [32 q][64 k] once (log2e-scaled by proj): 256 thr x 16B
    {
        const int gr = t >> 3, gc = (t & 7) * 8;
        const _Float16* src = gb + ((size_t)b * NN + q0 + gr) * KP + gc;
        *(f16x8*)&g_s[gr][gc] = *(const f16x8*)src;
    }
    // preload f tile 0 into registers
    f16x8 fr0, fr1;
    {
        const _Float16* src = fb + ((size_t)b * NN + row) * KP + kq * 16;
        fr0 = *(const f16x8*)(src);
        fr1 = *(const f16x8*)(src + 8);
    }
    __syncthreads();   // g_s visible

    // hoist loop-invariant A-fragments of QK^T (waves 0,1 own q-stripe w*16)
    f16x8 ag[2];
    if (w < 2) {
        ag[0] = *(const f16x8*)&g_s[w * 16 + ln][quad * 8];
        ag[1] = *(const f16x8*)&g_s[w * 16 + ln][32 + quad * 8];
    }

    float m_run[4] = {-1e30f, -1e30f, -1e30f, -1e30f};
    float l_run[4] = {0.f, 0.f, 0.f, 0.f};   // per-lane PARTIAL row sums
    f32x4 acc[2][4] = {};
    f16x8 hv[4];

    #pragma unroll 1
    for (int mt = 0; mt < NN / 64; mt++) {
        const int m0 = mt * 64;

        // current f tile regs -> LDS
        *(f16x8*)&f_s[row][kq * 16]     = fr0;
        *(f16x8*)&f_s[row][kq * 16 + 8] = fr1;
        __syncthreads();   // barrier 1: f_s ready

        // prefetches: next f tile + this tile's hv ks=0 half
        {
            const int m0n = ((mt + 1) & 63) * 64;   // wrap: harmless reload
            const _Float16* srcf = fb + ((size_t)b * NN + m0n + row) * KP + kq * 16;
            fr0 = *(const f16x8*)(srcf);
            fr1 = *(const f16x8*)(srcf + 8);
            #pragma unroll
            for (int df = 0; df < 4; df++)
                hv[df] = *(const f16x8*)(hT +
                    ((size_t)b * CC + dbase + df * 16 + ln) * NN + m0 + quad * 8);
        }

        if (w < 2) {
            // ---- QK^T for this wave's 16-row q-stripe ----
            f32x4 S[4] = {};
            #pragma unroll
            for (int ks = 0; ks < 2; ks++) {
                #pragma unroll
                for (int mf = 0; mf < 4; mf++) {
                    f16x8 bf = *(const f16x8*)&f_s[mf * 16 + ln][ks * 32 + quad * 8];
                    S[mf] = MFMA16(ag[ks], bf, S[mf]);
                }
            }

            // ---- deferred-max online softmax, rows q = w*16 + quad*4 + r --
            float pmax[4];
            bool upd = false;
            #pragma unroll
            for (int r = 0; r < 4; r++) {
                pmax[r] = fmaxf(fmaxf(S[0][r], S[1][r]), fmaxf(S[2][r], S[3][r]));
                upd |= (pmax[r] > m_run[r] + 10.0f);
            }
            const bool wave_upd = (__ballot(upd) != 0ull);   // wave-uniform
            if (wave_upd) {
                #pragma unroll
                for (int r = 0; r < 4; r++) {
                    float mx   = max16(pmax[r]);
                    float mnew = fmaxf(m_run[r], mx);
                    float al   = fast_exp2(m_run[r] - mnew);
                    l_run[r] *= al;
                    m_run[r]  = mnew;
                    if (ln == 0) alpha_s[w * 16 + quad * 4 + r] = al;
                }
            }
            if (lane == 0) chg_s[w] = wave_upd ? 1.0f : 0.0f;
            #pragma unroll
            for (int r = 0; r < 4; r++) {
                float p0 = fast_exp2(S[0][r] - m_run[r]);
                float p1 = fast_exp2(S[1][r] - m_run[r]);
                float p2 = fast_exp2(S[2][r] - m_run[r]);
                float p3 = fast_exp2(S[3][r] - m_run[r]);
                l_run[r] += (p0 + p1) + (p2 + p3);   // lazy: reduced after loop
                f16x4 pk = { (_Float16)p0, (_Float16)p1, (_Float16)p2, (_Float16)p3 };
                *(f16x4*)&p_s[w * 16 + quad * 4 + r][ln * 4] = pk;   // permuted m'
            }
        }
        __syncthreads();   // barrier 2: p_s/chg_s/alpha_s visible (+ drain)

        // ---- rescale, gated per stripe (wave-uniform branches) ----
        {
            float chg[2] = { chg_s[0], chg_s[1] };
            #pragma unroll
            for (int qf = 0; qf < 2; qf++) {
                if (chg[qf] != 0.0f) {
                    #pragma unroll
                    for (int r = 0; r < 4; r++) {
                        float al = alpha_s[qf * 16 + quad * 4 + r];
                        #pragma unroll
                        for (int df = 0; df < 4; df++)
                            acc[qf][df][r] *= al;
                    }
                }
            }
        }

        // ---- PV ks=0 (hv holds ks0) ----
        #pragma unroll
        for (int qf = 0; qf < 2; qf++) {
            f16x8 ap = *(const f16x8*)&p_s[qf * 16 + ln][quad * 8];
            #pragma unroll
            for (int df = 0; df < 4; df++)
                acc[qf][df] = MFMA16(ap, hv[df], acc[qf][df]);
        }
        // reload hv with ks=1 half (covered by PV ks0 + co-resident blocks)
        #pragma unroll
        for (int df = 0; df < 4; df++)
            hv[df] = *(const f16x8*)(hT +
                ((size_t)b * CC + dbase + df * 16 + ln) * NN + m0 + 32 + quad * 8);
        // ---- PV ks=1 ----
        #pragma unroll
        for (int qf = 0; qf < 2; qf++) {
            f16x8 ap = *(const f16x8*)&p_s[qf * 16 + ln][32 + quad * 8];
            #pragma unroll
            for (int df = 0; df < 4; df++)
                acc[qf][df] = MFMA16(ap, hv[df], acc[qf][df]);
        }
    }

    // ---- finish l (deferred 16-lane reduce), exchange across waves ----
    if (w < 2) {
        #pragma unroll
        for (int r = 0; r < 4; r++) {
            float lt = sum16(l_run[r]);
            if (ln == 0) l_s[w * 16 + quad * 4 + r] = lt;
        }
    }
    __syncthreads();

    const float gam = gamma[0];
    #pragma unroll
    for (int qf = 0; qf < 2; qf++) {
        #pragma unroll
        for (int r = 0; r < 4; r++) {
            const int q = qf * 16 + quad * 4 + r;
            const float linv = 1.0f / l_s[q];
            #pragma unroll
            for (int df = 0; df < 4; df++) {
                const int d = dbase + df * 16 + ln;
                size_t idx = ((size_t)b * NN + q0 + q) * CC + d;
                out[idx] = fmaf(gam, acc[qf][df][r] * linv, inp[idx]);
            }
        }
    }
}

// ---------------------------------------------------------------------------
extern "C" void kernel_launch(void* const* d_in, const int* in_sizes, int n_in,
                              void* d_out, int out_size, void* d_ws, size_t ws_size,
                              hipStream_t stream) {
    const float* input = (const float*)d_in[0];
    const float* nms   = (const float*)d_in[1];
    const float* WF    = (const float*)d_in[2];
    const float* WG    = (const float*)d_in[3];
    const float* WH    = (const float*)d_in[4];
    const float* gamma = (const float*)d_in[5];
    float* out = (float*)d_out;

    // workspace: W16 (192 KB) | fb16 (4 MB) | gb16 (4 MB) | hT16 (16 MB)
    char* ws = (char*)d_ws;
    _Float16* W16  = (_Float16*)ws;
    _Float16* fb16 = (_Float16*)(ws + 196608);
    _Float16* gb16 = (_Float16*)(ws + 196608 + 4194304);
    _Float16* hT16 = (_Float16*)(ws + 196608 + 2 * 4194304);

    wconv_kernel<<<96, 256, 0, stream>>>(WF, WG, WH, W16);
    proj16_kernel<<<dim3(NN / 64, BB), 256, 0, stream>>>(nms, W16, fb16, gb16, hT16);
    attn16_kernel<<<dim3(BB, NN / 32), 256, 0, stream>>>(
        fb16, gb16, hT16, input, gamma, out);
}

// Round 6
// 284.057 us; speedup vs baseline: 1.9455x; 1.3129x over previous
//
#include <hip/hip_runtime.h>
#include <hip/hip_bf16.h>

#define BB 8
#define CC 256
#define NN 4096
#define KP 64   // projection dim K = C/4
#define LOG2E 1.44269504088896f

typedef _Float16 f16x8 __attribute__((ext_vector_type(8)));
typedef _Float16 f16x4 __attribute__((ext_vector_type(4)));
typedef float    f32x4 __attribute__((ext_vector_type(4)));

#define MFMA16(a, b, c) __builtin_amdgcn_mfma_f32_16x16x32_f16((a), (b), (c), 0, 0, 0)

// exp2 (g is pre-scaled by log2e in proj, so softmax runs in base-2)
__device__ __forceinline__ float fast_exp2(float x) {
#if __has_builtin(__builtin_amdgcn_exp2f)
    return __builtin_amdgcn_exp2f(x);
#else
    return __expf(x * 0.69314718055994531f);
#endif
}

// 16-lane (DPP-row) rotate reductions: VALU-speed, off the LDS pipe
template<int CTRL>
__device__ __forceinline__ float dpp_ror_f(float x) {
    return __int_as_float(__builtin_amdgcn_update_dpp(
        0, __float_as_int(x), CTRL, 0xF, 0xF, true));
}
__device__ __forceinline__ float max16(float x) {
    x = fmaxf(x, dpp_ror_f<0x128>(x));
    x = fmaxf(x, dpp_ror_f<0x124>(x));
    x = fmaxf(x, dpp_ror_f<0x122>(x));
    x = fmaxf(x, dpp_ror_f<0x121>(x));
    return x;
}
__device__ __forceinline__ float sum16(float x) {
    x += dpp_ror_f<0x128>(x);
    x += dpp_ror_f<0x124>(x);
    x += dpp_ror_f<0x122>(x);
    x += dpp_ror_f<0x121>(x);
    return x;
}

// ---------------------------------------------------------------------------
// Kernel 0: WF|WG|WH fp32 -> concatenated fp16 W16[384][256].
// ---------------------------------------------------------------------------
__global__ __launch_bounds__(256) void wconv_kernel(
    const float* __restrict__ WF, const float* __restrict__ WG,
    const float* __restrict__ WH, _Float16* __restrict__ W16)
{
    int gid = blockIdx.x * 256 + threadIdx.x;
    int i4  = gid * 4;
    const float* src;
    if (i4 < 64 * CC)        src = WF + i4;
    else if (i4 < 128 * CC)  src = WG + (i4 - 64 * CC);
    else                     src = WH + (i4 - 128 * CC);
    float4 v = *(const float4*)src;
    f16x4 o = { (_Float16)v.x, (_Float16)v.y, (_Float16)v.z, (_Float16)v.w };
    *(f16x4*)(W16 + i4) = o;
}

// ---------------------------------------------------------------------------
// Kernel 1: fp16 MFMA projection, 64-token tiles.
// D[384 out][64 tok] = W16 x feat. Wave w owns out-rows [w*96, w*96+96).
// g rows are pre-scaled by log2e (softmax invariant; lets attn use raw exp2).
// hT is stored sigma-permuted within each 64-token tile (col c <-> token
// (c&3)*16 + (c>>2)), matching p_s's permuted column order in attention.
// ---------------------------------------------------------------------------
__global__ __launch_bounds__(256, 3) void proj16_kernel(
    const float* __restrict__ feat, const _Float16* __restrict__ W16,
    _Float16* __restrict__ fb, _Float16* __restrict__ gb,
    _Float16* __restrict__ hT)
{
    __shared__ __align__(16) _Float16 ft[64][264];
    const int b = blockIdx.y, n0 = blockIdx.x * 64, t = threadIdx.x;

    // stage feat[b][:, n0..n0+63] -> ft[tok][c] fp16 (transpose + convert)
    #pragma unroll
    for (int i = 0; i < 16; i++) {
        int v = t + i * 256, c = v >> 4, nq = v & 15;
        float4 x = *(const float4*)(feat + ((size_t)b * CC + c) * NN + n0 + nq * 4);
        ft[nq * 4 + 0][c] = (_Float16)x.x;
        ft[nq * 4 + 1][c] = (_Float16)x.y;
        ft[nq * 4 + 2][c] = (_Float16)x.z;
        ft[nq * 4 + 3][c] = (_Float16)x.w;
    }
    __syncthreads();

    const int w = t >> 6, lane = t & 63, quad = lane >> 4, ln = lane & 15;
    const int rowbase = w * 96;

    f32x4 acc[6][4] = {};
    #pragma unroll
    for (int ks = 0; ks < 8; ks++) {
        const int c0 = ks * 32;
        f16x8 bfr[4];
        #pragma unroll
        for (int tf = 0; tf < 4; tf++)
            bfr[tf] = *(const f16x8*)&ft[tf * 16 + ln][c0 + quad * 8];
        #pragma unroll
        for (int af = 0; af < 6; af++) {
            f16x8 a = *(const f16x8*)(W16 + (size_t)(rowbase + af * 16 + ln) * CC + c0 + quad * 8);
            #pragma unroll
            for (int tf = 0; tf < 4; tf++)
                acc[af][tf] = MFMA16(a, bfr[tf], acc[af][tf]);
        }
    }

    // C/D layout: col(tok)=ln, row(out)=quad*4+r
    #pragma unroll
    for (int af = 0; af < 6; af++) {
        const int orow0 = rowbase + af * 16 + quad * 4;   // wave-uniform range
        if (orow0 < 64) {
            #pragma unroll
            for (int tf = 0; tf < 4; tf++) {
                const int tok = n0 + tf * 16 + ln;
                f16x4 pk = { (_Float16)acc[af][tf][0], (_Float16)acc[af][tf][1],
                             (_Float16)acc[af][tf][2], (_Float16)acc[af][tf][3] };
                *(f16x4*)(fb + ((size_t)b * NN + tok) * KP + orow0) = pk;
            }
        } else if (orow0 < 128) {
            #pragma unroll
            for (int tf = 0; tf < 4; tf++) {
                const int tok = n0 + tf * 16 + ln;
                f16x4 pk = { (_Float16)(acc[af][tf][0] * LOG2E),
                             (_Float16)(acc[af][tf][1] * LOG2E),
                             (_Float16)(acc[af][tf][2] * LOG2E),
                             (_Float16)(acc[af][tf][3] * LOG2E) };
                *(f16x4*)(gb + ((size_t)b * NN + tok) * KP + (orow0 - 64)) = pk;
            }
        } else {
            #pragma unroll
            for (int r = 0; r < 4; r++) {
                const int d = orow0 - 128 + r;
                f16x4 pk = { (_Float16)acc[af][0][r], (_Float16)acc[af][1][r],
                             (_Float16)acc[af][2][r], (_Float16)acc[af][3][r] };
                *(f16x4*)(hT + ((size_t)b * CC + d) * NN + n0 + ln * 4) = pk;
            }
        }
    }
}

// ---------------------------------------------------------------------------
// Kernel 2: fp16 MFMA flash attention, Tq=64, Tm=128, 4 symmetric waves.
// AMORTIZATION build. Evidence (r1/r2/r5): wall ~= 2700 cyc x block-iters/CU,
// nearly independent of occupancy / VALU work / prefetch depth -> each
// barrier-delimited phase has a ~2300-cyc fixed cost. So: HALVE the phase
// count (32 m-iters of 128 tokens, was 64 of 64) and double per-phase work.
// Per wave per iter: QK 16 MFMA (S[8]), PV 64 MFMA over 4 ks-segments with
// hv[4][4] (64 VGPR) fully prefetched after barrier 1. __launch_bounds__
// (256,2) -> 256-VGPR budget, no spill (peak ~205). 2 blocks/CU (LDS 46KB).
// p_s[64][136]: cols [0,64) = sub-tile-0 permuted (m' = ln*4+mf), cols
// [64,128) = sub-tile-1; matches hT's per-64-token permutation (m0 is
// 128-aligned). Deferred-max softmax (THR=10) + lazy l-reduce as r1.
// ---------------------------------------------------------------------------
__global__ __launch_bounds__(256, 2) void attn16_kernel(
    const _Float16* __restrict__ fb, const _Float16* __restrict__ gb,
    const _Float16* __restrict__ hT, const float* __restrict__ inp,
    const float* __restrict__ gamma, float* __restrict__ out)
{
    __shared__ __align__(16) _Float16 g_s[64][72];
    __shared__ __align__(16) _Float16 f_s[128][72];
    __shared__ __align__(16) _Float16 p_s[64][136];
    __shared__ float alpha_s[64];
    __shared__ float l_s[64];
    __shared__ float chg_s[4];

    const int b = blockIdx.x, q0 = blockIdx.y * 64, t = threadIdx.x;
    const int w = t >> 6, lane = t & 63, quad = lane >> 4, ln = lane & 15;
    const int srow = t >> 1, scol = (t & 1) * 32;   // f staging: 128 rows x 64B
    const int dbase = w * 64;

    // stage g tile [64 q][64 k] once (already log2e-scaled by proj)
    {
        const int gr = t >> 2, gq = t & 3;
        const _Float16* src = gb + ((size_t)b * NN + q0 + gr) * KP + gq * 16;
        *(f16x8*)&g_s[gr][gq * 16]     = *(const f16x8*)(src);
        *(f16x8*)&g_s[gr][gq * 16 + 8] = *(const f16x8*)(src + 8);
    }
    // preload f tile 0 (128 tokens) into registers
    f16x8 fr[4];
    {
        const _Float16* src = fb + ((size_t)b * NN + srow) * KP + scol;
        #pragma unroll
        for (int j = 0; j < 4; j++) fr[j] = *(const f16x8*)(src + j * 8);
    }
    __syncthreads();   // g_s visible

    // hoist loop-invariant A-fragments of QK^T
    f16x8 ag[2];
    ag[0] = *(const f16x8*)&g_s[w * 16 + ln][quad * 8];
    ag[1] = *(const f16x8*)&g_s[w * 16 + ln][32 + quad * 8];

    float m_run[4] = {-1e30f, -1e30f, -1e30f, -1e30f};
    float l_run[4] = {0.f, 0.f, 0.f, 0.f};   // per-lane PARTIAL row sums
    f32x4 acc[4][4] = {};
    f16x8 hv[4][4];

    #pragma unroll 1
    for (int mt = 0; mt < NN / 128; mt++) {
        const int m0 = mt * 128;

        // current f tile regs -> LDS
        #pragma unroll
        for (int j = 0; j < 4; j++)
            *(f16x8*)&f_s[srow][scol + j * 8] = fr[j];
        __syncthreads();   // barrier 1: f_s ready

        // prefetches: next f tile + this tile's hv (all 4 ks-segments).
        // They drain at barrier 2, covered by QK^T + softmax.
        {
            const int m0n = ((mt + 1) & 31) * 128;   // wrap: harmless reload
            const _Float16* srcf = fb + ((size_t)b * NN + m0n + srow) * KP + scol;
            #pragma unroll
            for (int j = 0; j < 4; j++) fr[j] = *(const f16x8*)(srcf + j * 8);
            #pragma unroll
            for (int ks = 0; ks < 4; ks++)
                #pragma unroll
                for (int df = 0; df < 4; df++)
                    hv[ks][df] = *(const f16x8*)(hT +
                        ((size_t)b * CC + dbase + df * 16 + ln) * NN + m0 + ks * 32 + quad * 8);
        }

        // ---- QK^T for this wave's q-stripe: 8 m-fragments ----
        f32x4 S[8] = {};
        #pragma unroll
        for (int ks = 0; ks < 2; ks++) {
            #pragma unroll
            for (int mf = 0; mf < 8; mf++) {
                f16x8 bf = *(const f16x8*)&f_s[mf * 16 + ln][ks * 32 + quad * 8];
                S[mf] = MFMA16(ag[ks], bf, S[mf]);
            }
        }

        // ---- deferred-max online softmax (base-2), rows q = w*16+quad*4+r --
        float pmax[4];
        bool upd = false;
        #pragma unroll
        for (int r = 0; r < 4; r++) {
            float mx = fmaxf(fmaxf(fmaxf(S[0][r], S[1][r]), fmaxf(S[2][r], S[3][r])),
                             fmaxf(fmaxf(S[4][r], S[5][r]), fmaxf(S[6][r], S[7][r])));
            pmax[r] = mx;
            upd |= (mx > m_run[r] + 10.0f);
        }
        const bool wave_upd = (__ballot(upd) != 0ull);   // wave-uniform
        if (wave_upd) {
            #pragma unroll
            for (int r = 0; r < 4; r++) {
                float mx   = max16(pmax[r]);
                float mnew = fmaxf(m_run[r], mx);
                float al   = fast_exp2(m_run[r] - mnew);
                l_run[r] *= al;
                m_run[r]  = mnew;
                if (ln == 0) alpha_s[w * 16 + quad * 4 + r] = al;
            }
        }
        if (lane == 0) chg_s[w] = wave_upd ? 1.0f : 0.0f;
        #pragma unroll
        for (int r = 0; r < 4; r++) {
            float p[8];
            #pragma unroll
            for (int mf = 0; mf < 8; mf++) p[mf] = fast_exp2(S[mf][r] - m_run[r]);
            l_run[r] += ((p[0] + p[1]) + (p[2] + p[3]))
                      + ((p[4] + p[5]) + (p[6] + p[7]));   // lazy reduce at end
            const int qrow = w * 16 + quad * 4 + r;
            f16x4 pk0 = { (_Float16)p[0], (_Float16)p[1], (_Float16)p[2], (_Float16)p[3] };
            f16x4 pk1 = { (_Float16)p[4], (_Float16)p[5], (_Float16)p[6], (_Float16)p[7] };
            *(f16x4*)&p_s[qrow][ln * 4]      = pk0;   // sub-tile 0, m' = ln*4+mf
            *(f16x4*)&p_s[qrow][64 + ln * 4] = pk1;   // sub-tile 1
        }
        __syncthreads();   // barrier 2: p_s/chg_s/alpha_s visible (+ drain)

        // ---- rescale, gated per wave-of-origin (wave-uniform branches) ----
        {
            float chg[4] = { chg_s[0], chg_s[1], chg_s[2], chg_s[3] };
            #pragma unroll
            for (int qf = 0; qf < 4; qf++) {
                if (chg[qf] != 0.0f) {
                    #pragma unroll
                    for (int r = 0; r < 4; r++) {
                        float al = alpha_s[qf * 16 + quad * 4 + r];
                        #pragma unroll
                        for (int df = 0; df < 4; df++)
                            acc[qf][df][r] *= al;
                    }
                }
            }
        }

        // ---- PV: P x h^T over this wave's 64 channels, 4 ks-segments ----
        #pragma unroll
        for (int ks = 0; ks < 4; ks++) {
            #pragma unroll
            for (int qf = 0; qf < 4; qf++) {
                f16x8 ap = *(const f16x8*)&p_s[qf * 16 + ln][ks * 32 + quad * 8];
                #pragma unroll
                for (int df = 0; df < 4; df++)
                    acc[qf][df] = MFMA16(ap, hv[ks][df], acc[qf][df]);
            }
        }
    }

    // ---- finish l (deferred 16-lane reduce), exchange across waves ----
    #pragma unroll
    for (int r = 0; r < 4; r++) {
        float lt = sum16(l_run[r]);
        if (ln == 0) l_s[w * 16 + quad * 4 + r] = lt;
    }
    __syncthreads();

    const float gam = gamma[0];
    #pragma unroll
    for (int qf = 0; qf < 4; qf++) {
        #pragma unroll
        for (int r = 0; r < 4; r++) {
            const int q = qf * 16 + quad * 4 + r;
            const float linv = 1.0f / l_s[q];
            #pragma unroll
            for (int df = 0; df < 4; df++) {
                const int d = dbase + df * 16 + ln;
                size_t idx = ((size_t)b * NN + q0 + q) * CC + d;
                out[idx] = fmaf(gam, acc[qf][df][r] * linv, inp[idx]);
            }
        }
    }
}

// ---------------------------------------------------------------------------
extern "C" void kernel_launch(void* const* d_in, const int* in_sizes, int n_in,
                              void* d_out, int out_size, void* d_ws, size_t ws_size,
                              hipStream_t stream) {
    const float* input = (const float*)d_in[0];
    const float* nms   = (const float*)d_in[1];
    const float* WF    = (const float*)d_in[2];
    const float* WG    = (const float*)d_in[3];
    const float* WH    = (const float*)d_in[4];
    const float* gamma = (const float*)d_in[5];
    float* out = (float*)d_out;

    // workspace: W16 (192 KB) | fb16 (4 MB) | gb16 (4 MB) | hT16 (16 MB)
    char* ws = (char*)d_ws;
    _Float16* W16  = (_Float16*)ws;
    _Float16* fb16 = (_Float16*)(ws + 196608);
    _Float16* gb16 = (_Float16*)(ws + 196608 + 4194304);
    _Float16* hT16 = (_Float16*)(ws + 196608 + 2 * 4194304);

    wconv_kernel<<<96, 256, 0, stream>>>(WF, WG, WH, W16);
    proj16_kernel<<<dim3(NN / 64, BB), 256, 0, stream>>>(nms, W16, fb16, gb16, hT16);
    attn16_kernel<<<dim3(BB, NN / 64), 256, 0, stream>>>(
        fb16, gb16, hT16, input, gamma, out);
}

// Round 8
// 256.697 us; speedup vs baseline: 2.1528x; 1.1066x over previous
//
#include <hip/hip_runtime.h>
#include <hip/hip_bf16.h>

#define BB 8
#define CC 256
#define NN 4096
#define KP 64   // projection dim K = C/4
#define LOG2E 1.44269504088896f

typedef _Float16 f16x8 __attribute__((ext_vector_type(8)));
typedef _Float16 f16x4 __attribute__((ext_vector_type(4)));
typedef float    f32x4 __attribute__((ext_vector_type(4)));

#define MFMA16(a, b, c) __builtin_amdgcn_mfma_f32_16x16x32_f16((a), (b), (c), 0, 0, 0)

// exp2 (g is pre-scaled by log2e in proj, so softmax runs in base-2)
__device__ __forceinline__ float fast_exp2(float x) {
#if __has_builtin(__builtin_amdgcn_exp2f)
    return __builtin_amdgcn_exp2f(x);
#else
    return __expf(x * 0.69314718055994531f);
#endif
}

// lgkm-only workgroup barrier (T4-lite). __syncthreads makes hipcc emit
// s_waitcnt vmcnt(0) lgkmcnt(0) before s_barrier, force-draining the hv/fr
// register prefetches every iteration. Our cross-wave data (f_s/p_s/alpha_s)
// moves ONLY through LDS, so visibility needs lgkmcnt(0) only; register
// loads drain at their USE via the compiler's own counted vmcnt. "memory"
// clobbers fence compiler code motion on both sides (m201 pattern).
// Outstanding vmcnt across s_barrier is architecturally legal (AITER's
// hand-asm K-loop does s_waitcnt vmcnt(2/5/12) across barriers, guide s5).
__device__ __forceinline__ void barrier_lgkm() {
    asm volatile("s_waitcnt lgkmcnt(0)" ::: "memory");
    __builtin_amdgcn_s_barrier();
    asm volatile("" ::: "memory");
}

// 16-lane (DPP-row) rotate reductions: VALU-speed, off the LDS pipe
template<int CTRL>
__device__ __forceinline__ float dpp_ror_f(float x) {
    return __int_as_float(__builtin_amdgcn_update_dpp(
        0, __float_as_int(x), CTRL, 0xF, 0xF, true));
}
__device__ __forceinline__ float max16(float x) {
    x = fmaxf(x, dpp_ror_f<0x128>(x));
    x = fmaxf(x, dpp_ror_f<0x124>(x));
    x = fmaxf(x, dpp_ror_f<0x122>(x));
    x = fmaxf(x, dpp_ror_f<0x121>(x));
    return x;
}
__device__ __forceinline__ float sum16(float x) {
    x += dpp_ror_f<0x128>(x);
    x += dpp_ror_f<0x124>(x);
    x += dpp_ror_f<0x122>(x);
    x += dpp_ror_f<0x121>(x);
    return x;
}

// ---------------------------------------------------------------------------
// Kernel 0: WF|WG|WH fp32 -> concatenated fp16 W16[384][256].
// ---------------------------------------------------------------------------
__global__ __launch_bounds__(256) void wconv_kernel(
    const float* __restrict__ WF, const float* __restrict__ WG,
    const float* __restrict__ WH, _Float16* __restrict__ W16)
{
    int gid = blockIdx.x * 256 + threadIdx.x;
    int i4  = gid * 4;
    const float* src;
    if (i4 < 64 * CC)        src = WF + i4;
    else if (i4 < 128 * CC)  src = WG + (i4 - 64 * CC);
    else                     src = WH + (i4 - 128 * CC);
    float4 v = *(const float4*)src;
    f16x4 o = { (_Float16)v.x, (_Float16)v.y, (_Float16)v.z, (_Float16)v.w };
    *(f16x4*)(W16 + i4) = o;
}

// ---------------------------------------------------------------------------
// Kernel 1: fp16 MFMA projection, 64-token tiles.
// D[384 out][64 tok] = W16 x feat. Wave w owns out-rows [w*96, w*96+96).
// g rows are pre-scaled by log2e (softmax invariant; lets attn use raw exp2).
// ---------------------------------------------------------------------------
__global__ __launch_bounds__(256, 3) void proj16_kernel(
    const float* __restrict__ feat, const _Float16* __restrict__ W16,
    _Float16* __restrict__ fb, _Float16* __restrict__ gb,
    _Float16* __restrict__ hT)
{
    __shared__ __align__(16) _Float16 ft[64][264];
    const int b = blockIdx.y, n0 = blockIdx.x * 64, t = threadIdx.x;

    // stage feat[b][:, n0..n0+63] -> ft[tok][c] fp16 (transpose + convert)
    #pragma unroll
    for (int i = 0; i < 16; i++) {
        int v = t + i * 256, c = v >> 4, nq = v & 15;
        float4 x = *(const float4*)(feat + ((size_t)b * CC + c) * NN + n0 + nq * 4);
        ft[nq * 4 + 0][c] = (_Float16)x.x;
        ft[nq * 4 + 1][c] = (_Float16)x.y;
        ft[nq * 4 + 2][c] = (_Float16)x.z;
        ft[nq * 4 + 3][c] = (_Float16)x.w;
    }
    __syncthreads();

    const int w = t >> 6, lane = t & 63, quad = lane >> 4, ln = lane & 15;
    const int rowbase = w * 96;

    f32x4 acc[6][4] = {};
    #pragma unroll
    for (int ks = 0; ks < 8; ks++) {
        const int c0 = ks * 32;
        f16x8 bfr[4];
        #pragma unroll
        for (int tf = 0; tf < 4; tf++)
            bfr[tf] = *(const f16x8*)&ft[tf * 16 + ln][c0 + quad * 8];
        #pragma unroll
        for (int af = 0; af < 6; af++) {
            f16x8 a = *(const f16x8*)(W16 + (size_t)(rowbase + af * 16 + ln) * CC + c0 + quad * 8);
            #pragma unroll
            for (int tf = 0; tf < 4; tf++)
                acc[af][tf] = MFMA16(a, bfr[tf], acc[af][tf]);
        }
    }

    // C/D layout: col(tok)=ln, row(out)=quad*4+r
    #pragma unroll
    for (int af = 0; af < 6; af++) {
        const int orow0 = rowbase + af * 16 + quad * 4;   // wave-uniform range
        if (orow0 < 64) {
            #pragma unroll
            for (int tf = 0; tf < 4; tf++) {
                const int tok = n0 + tf * 16 + ln;
                f16x4 pk = { (_Float16)acc[af][tf][0], (_Float16)acc[af][tf][1],
                             (_Float16)acc[af][tf][2], (_Float16)acc[af][tf][3] };
                *(f16x4*)(fb + ((size_t)b * NN + tok) * KP + orow0) = pk;
            }
        } else if (orow0 < 128) {
            #pragma unroll
            for (int tf = 0; tf < 4; tf++) {
                const int tok = n0 + tf * 16 + ln;
                f16x4 pk = { (_Float16)(acc[af][tf][0] * LOG2E),
                             (_Float16)(acc[af][tf][1] * LOG2E),
                             (_Float16)(acc[af][tf][2] * LOG2E),
                             (_Float16)(acc[af][tf][3] * LOG2E) };
                *(f16x4*)(gb + ((size_t)b * NN + tok) * KP + (orow0 - 64)) = pk;
            }
        } else {
            #pragma unroll
            for (int r = 0; r < 4; r++) {
                const int d = orow0 - 128 + r;
                f16x4 pk = { (_Float16)acc[af][0][r], (_Float16)acc[af][1][r],
                             (_Float16)acc[af][2][r], (_Float16)acc[af][3][r] };
                *(f16x4*)(hT + ((size_t)b * CC + d) * NN + n0 + ln * 4) = pk;
            }
        }
    }
}

// ---------------------------------------------------------------------------
// Kernel 2: fp16 MFMA flash attention, Tq=64, Tm=64, 4 symmetric waves.
// Round-1 structure EXACTLY (best measured: 154 us), with ONE isolated
// change: the two in-loop __syncthreads become lgkm-only barriers
// (barrier_lgkm). This removes the compiler's s_waitcnt vmcnt(0) drain at
// each barrier, letting the hv/fr register prefetches float across barriers
// and retire at first use via counted vmcnt (T4's "never drain to 0").
// Hazard audit (all preserved by lgkmcnt(0) at the separating barrier):
//   f_s  WAR: QK reads(t) < b2(t) < write(t+1)
//   p_s  WAR: PV reads(t) < b1(t+1) < write(t+1)
//   alpha/chg WAR: rescale reads(t) < b1(t+1) < writes(t+1)
// hv issued before fr so PV's auto-vmcnt leaves fr in flight.
// Deferred-max softmax (THR=10, base-2) + lazy l-reduction as before.
// ---------------------------------------------------------------------------
__global__ __launch_bounds__(256, 2) void attn16_kernel(
    const _Float16* __restrict__ fb, const _Float16* __restrict__ gb,
    const _Float16* __restrict__ hT, const float* __restrict__ inp,
    const float* __restrict__ gamma, float* __restrict__ out)
{
    __shared__ __align__(16) _Float16 g_s[64][72];
    __shared__ __align__(16) _Float16 f_s[64][72];
    __shared__ __align__(16) _Float16 p_s[64][72];
    __shared__ float alpha_s[64];
    __shared__ float l_s[64];
    __shared__ float chg_s[4];

    const int b = blockIdx.x, q0 = blockIdx.y * 64, t = threadIdx.x;
    const int w = t >> 6, lane = t & 63, quad = lane >> 4, ln = lane & 15;
    const int row = t >> 2, kq = t & 3;
    const int dbase = w * 64;

    // stage g tile [64 q][64 k] once (already log2e-scaled by proj)
    {
        const _Float16* src = gb + ((size_t)b * NN + q0 + row) * KP + kq * 16;
        *(f16x8*)&g_s[row][kq * 16]     = *(const f16x8*)(src);
        *(f16x8*)&g_s[row][kq * 16 + 8] = *(const f16x8*)(src + 8);
    }
    // preload f tile 0 into registers
    f16x8 fr0, fr1;
    {
        const _Float16* src = fb + ((size_t)b * NN + row) * KP + kq * 16;
        fr0 = *(const f16x8*)(src);
        fr1 = *(const f16x8*)(src + 8);
    }
    __syncthreads();   // g_s visible (prologue, once: full sync is fine)

    // hoist loop-invariant A-fragments of QK^T
    f16x8 ag[2];
    ag[0] = *(const f16x8*)&g_s[w * 16 + ln][quad * 8];
    ag[1] = *(const f16x8*)&g_s[w * 16 + ln][32 + quad * 8];

    float m_run[4] = {-1e30f, -1e30f, -1e30f, -1e30f};
    float l_run[4] = {0.f, 0.f, 0.f, 0.f};   // per-lane PARTIAL row sums
    f32x4 acc[4][4] = {};
    f16x8 hv[2][4];

    #pragma unroll 1
    for (int mt = 0; mt < NN / 64; mt++) {
        const int m0 = mt * 64;

        // current f tile regs -> LDS
        *(f16x8*)&f_s[row][kq * 16]     = fr0;
        *(f16x8*)&f_s[row][kq * 16 + 8] = fr1;
        barrier_lgkm();   // barrier 1: f_s ready (no vmcnt drain)

        // issue prefetches NOW: hv first (used at PV this iter), fr after
        // (used at f_s write next iter) -> PV's counted vmcnt leaves fr live.
        {
            #pragma unroll
            for (int ks = 0; ks < 2; ks++)
                #pragma unroll
                for (int df = 0; df < 4; df++)
                    hv[ks][df] = *(const f16x8*)(hT +
                        ((size_t)b * CC + dbase + df * 16 + ln) * NN + m0 + ks * 32 + quad * 8);
            const int m0n = ((mt + 1) & 63) * 64;   // wrap: harmless reload
            const _Float16* srcf = fb + ((size_t)b * NN + m0n + row) * KP + kq * 16;
            fr0 = *(const f16x8*)(srcf);
            fr1 = *(const f16x8*)(srcf + 8);
        }

        // ---- QK^T for this wave's q-stripe ----
        f32x4 S[4] = {};
        #pragma unroll
        for (int ks = 0; ks < 2; ks++) {
            #pragma unroll
            for (int mf = 0; mf < 4; mf++) {
                f16x8 bf = *(const f16x8*)&f_s[mf * 16 + ln][ks * 32 + quad * 8];
                S[mf] = MFMA16(ag[ks], bf, S[mf]);
            }
        }

        // ---- deferred-max online softmax (base-2), rows q = w*16+quad*4+r --
        float pmax[4];
        bool upd = false;
        #pragma unroll
        for (int r = 0; r < 4; r++) {
            pmax[r] = fmaxf(fmaxf(S[0][r], S[1][r]), fmaxf(S[2][r], S[3][r]));
            upd |= (pmax[r] > m_run[r] + 10.0f);
        }
        const bool wave_upd = (__ballot(upd) != 0ull);   // wave-uniform
        if (wave_upd) {
            #pragma unroll
            for (int r = 0; r < 4; r++) {
                float mx   = max16(pmax[r]);
                float mnew = fmaxf(m_run[r], mx);
                float al   = fast_exp2(m_run[r] - mnew);
                l_run[r] *= al;
                m_run[r]  = mnew;
                if (ln == 0) alpha_s[w * 16 + quad * 4 + r] = al;
            }
        }
        if (lane == 0) chg_s[w] = wave_upd ? 1.0f : 0.0f;
        #pragma unroll
        for (int r = 0; r < 4; r++) {
            float p0 = fast_exp2(S[0][r] - m_run[r]);
            float p1 = fast_exp2(S[1][r] - m_run[r]);
            float p2 = fast_exp2(S[2][r] - m_run[r]);
            float p3 = fast_exp2(S[3][r] - m_run[r]);
            l_run[r] += (p0 + p1) + (p2 + p3);   // per-lane partial, reduced at end
            f16x4 pk = { (_Float16)p0, (_Float16)p1, (_Float16)p2, (_Float16)p3 };
            *(f16x4*)&p_s[w * 16 + quad * 4 + r][ln * 4] = pk;   // permuted col m' = ln*4 + mf
        }
        barrier_lgkm();   // barrier 2: p_s/chg_s/alpha_s visible (no vmcnt drain)

        // ---- rescale, gated per wave-of-origin (wave-uniform branches) ----
        {
            float chg[4] = { chg_s[0], chg_s[1], chg_s[2], chg_s[3] };
            #pragma unroll
            for (int qf = 0; qf < 4; qf++) {
                if (chg[qf] != 0.0f) {
                    #pragma unroll
                    for (int r = 0; r < 4; r++) {
                        float al = alpha_s[qf * 16 + quad * 4 + r];
                        #pragma unroll
                        for (int df = 0; df < 4; df++)
                            acc[qf][df][r] *= al;
                    }
                }
            }
        }

        // ---- PV: P x h^T over this wave's 64 channels ----
        #pragma unroll
        for (int ks = 0; ks < 2; ks++) {
            #pragma unroll
            for (int qf = 0; qf < 4; qf++) {
                f16x8 ap = *(const f16x8*)&p_s[qf * 16 + ln][ks * 32 + quad * 8];
                #pragma unroll
                for (int df = 0; df < 4; df++)
                    acc[qf][df] = MFMA16(ap, hv[ks][df], acc[qf][df]);
            }
        }
    }

    // ---- finish l (deferred 16-lane reduce), exchange across waves ----
    #pragma unroll
    for (int r = 0; r < 4; r++) {
        float lt = sum16(l_run[r]);
        if (ln == 0) l_s[w * 16 + quad * 4 + r] = lt;
    }
    __syncthreads();   // epilogue, once: full sync is fine

    const float gam = gamma[0];
    #pragma unroll
    for (int qf = 0; qf < 4; qf++) {
        #pragma unroll
        for (int r = 0; r < 4; r++) {
            const int q = qf * 16 + quad * 4 + r;
            const float linv = 1.0f / l_s[q];
            #pragma unroll
            for (int df = 0; df < 4; df++) {
                const int d = dbase + df * 16 + ln;
                size_t idx = ((size_t)b * NN + q0 + q) * CC + d;
                out[idx] = fmaf(gam, acc[qf][df][r] * linv, inp[idx]);
            }
        }
    }
}

// ---------------------------------------------------------------------------
extern "C" void kernel_launch(void* const* d_in, const int* in_sizes, int n_in,
                              void* d_out, int out_size, void* d_ws, size_t ws_size,
                              hipStream_t stream) {
    const float* input = (const float*)d_in[0];
    const float* nms   = (const float*)d_in[1];
    const float* WF    = (const float*)d_in[2];
    const float* WG    = (const float*)d_in[3];
    const float* WH    = (const float*)d_in[4];
    const float* gamma = (const float*)d_in[5];
    float* out = (float*)d_out;

    // workspace: W16 (192 KB) | fb16 (4 MB) | gb16 (4 MB) | hT16 (16 MB)
    char* ws = (char*)d_ws;
    _Float16* W16  = (_Float16*)ws;
    _Float16* fb16 = (_Float16*)(ws + 196608);
    _Float16* gb16 = (_Float16*)(ws + 196608 + 4194304);
    _Float16* hT16 = (_Float16*)(ws + 196608 + 2 * 4194304);

    wconv_kernel<<<96, 256, 0, stream>>>(WF, WG, WH, W16);
    proj16_kernel<<<dim3(NN / 64, BB), 256, 0, stream>>>(nms, W16, fb16, gb16, hT16);
    attn16_kernel<<<dim3(BB, NN / 64), 256, 0, stream>>>(
        fb16, gb16, hT16, input, gamma, out);
}